// Round 8
// baseline (1364.477 us; speedup 1.0000x reference)
//
#include <hip/hip_runtime.h>

#define N_NODES 100000
#define N_EDGES 600000
#define IN_DIM 128
#define EDGE_DIM 32
#define HIDDEN 128
#define NBLK 391  // ceil(N_NODES/256)

typedef __attribute__((ext_vector_type(4))) float f32x4;
typedef _Float16 f16x2 __attribute__((ext_vector_type(2)));
typedef _Float16 f16x4 __attribute__((ext_vector_type(4)));
typedef _Float16 f16x8 __attribute__((ext_vector_type(8)));

#define SRC_MASK 131071  // 2^17-1; src<100000 fits

// ===========================================================================
// CSR build
// ===========================================================================
__global__ void hist_kernel(const int* __restrict__ dst, int* __restrict__ cnt) {
    int e = blockIdx.x * blockDim.x + threadIdx.x;
    if (e < N_EDGES) atomicAdd(&cnt[dst[e]], 1);
}

__global__ void scan1_kernel(const int* __restrict__ cnt,
                             int* __restrict__ scanout, int* __restrict__ bsum) {
    __shared__ int s[256];
    int tid = threadIdx.x;
    int i = blockIdx.x * 256 + tid;
    int v = (i < N_NODES) ? cnt[i] : 0;
    s[tid] = v;
    __syncthreads();
#pragma unroll
    for (int off = 1; off < 256; off <<= 1) {
        int t = 0;
        if (tid >= off) t = s[tid - off];
        __syncthreads();
        if (tid >= off) s[tid] += t;
        __syncthreads();
    }
    if (i < N_NODES) scanout[i] = s[tid];
    if (tid == 255) bsum[blockIdx.x] = s[255];
}

__global__ void scan2_kernel(int* __restrict__ bsum) {
    __shared__ int s[512];
    int tid = threadIdx.x;
    int v = (tid < NBLK) ? bsum[tid] : 0;
    s[tid] = v;
    __syncthreads();
#pragma unroll
    for (int off = 1; off < 512; off <<= 1) {
        int t = 0;
        if (tid >= off) t = s[tid - off];
        __syncthreads();
        if (tid >= off) s[tid] += t;
        __syncthreads();
    }
    if (tid < NBLK) bsum[tid] = s[tid] - v;  // exclusive
}

__global__ void scan3_kernel(const int* __restrict__ cnt,
                             const int* __restrict__ scanout,
                             const int* __restrict__ bsum,
                             int* __restrict__ rowptr, int* __restrict__ cur) {
    int i = blockIdx.x * 256 + threadIdx.x;
    if (i < N_NODES) {
        int excl = scanout[i] + bsum[i >> 8] - cnt[i];
        rowptr[i] = excl;
        cur[i] = excl;
    }
    if (i == 0) rowptr[N_NODES] = N_EDGES;
}

// pk[pos] = { src | (dst&31)<<25 , edge id } ; pdst[pos] = dst
// (dst&31) == dst - 32*(dst>>5) == local node id within the 32-aligned block
__global__ void fill_kernel(const int* __restrict__ src, const int* __restrict__ dst,
                            int* __restrict__ cur, int2* __restrict__ pk,
                            int* __restrict__ pdst) {
    int e = blockIdx.x * blockDim.x + threadIdx.x;
    if (e < N_EDGES) {
        int d = dst[e];
        int pos = atomicAdd(&cur[d], 1);
        int2 v;
        v.x = src[e] | ((d & 31) << 25);
        v.y = e;
        pk[pos] = v;
        pdst[pos] = d;
    }
}

// ===========================================================================
// x -> fp16 copy
// ===========================================================================
__global__ void xb_kernel(const float* __restrict__ x, _Float16* __restrict__ xb) {
    int i = blockIdx.x * 256 + threadIdx.x;  // over N*H/2 float2
    if (i < N_NODES * HIDDEN / 2) {
        float2 v = ((const float2*)x)[i];
        f16x2 o;
        o.x = (_Float16)v.x;
        o.y = (_Float16)v.y;
        *(f16x2*)&xb[i * 2] = o;
    }
}

// ===========================================================================
// eamb[n][32] = fp16 mean of ea over in-edges. Block-cooperative:
// 32 nodes/block, 4 waves walk the block's contiguous CSR range jointly,
// 16 edges per wave-step (8-deep x 2 half-wave slots), LDS fp32 accum.
// ds_add bank = k (lane&31): conflict-free.
// ===========================================================================
__global__ __launch_bounds__(256) void eam_kernel(const int* __restrict__ rowptr,
                                                  const int2* __restrict__ pk,
                                                  const float* __restrict__ ea,
                                                  _Float16* __restrict__ eamb) {
    __shared__ float s_e[32][EDGE_DIM];  // 4 KB
    __shared__ int s_rp[33];
    int t = threadIdx.x;
    int n0 = blockIdx.x * 32;
    if (t <= 32) s_rp[t] = rowptr[n0 + t];
    for (int i = t; i < 32 * EDGE_DIM; i += 256) ((float*)s_e)[i] = 0.f;
    __syncthreads();

    int E0 = s_rp[0], E1 = s_rp[32];
    int g = t >> 6;
    int lane = t & 63;
    int sub = lane >> 5;   // half-wave edge slot
    int k = lane & 31;

    for (int pos = E0 + g * 16; pos < E1; pos += 64) {
        int c = E1 - pos; c = c > 16 ? 16 : c;
        int2 pv[8];
        float va[8];
#pragma unroll
        for (int u = 0; u < 8; ++u) {
            int idx = 2 * u + sub;
            if (idx < c) pv[u] = pk[pos + idx];
        }
#pragma unroll
        for (int u = 0; u < 8; ++u) {
            int idx = 2 * u + sub;
            if (idx < c) va[u] = ea[pv[u].y * EDGE_DIM + k];
        }
#pragma unroll
        for (int u = 0; u < 8; ++u) {
            int idx = 2 * u + sub;
            if (idx < c) {
                int nl = ((unsigned)pv[u].x >> 25) & 31;
                atomicAdd(&s_e[nl][k], va[u]);
            }
        }
    }
    __syncthreads();

    for (int i = t; i < 32 * EDGE_DIM; i += 256) {
        int nl = i >> 5;
        int d = s_rp[nl + 1] - s_rp[nl];
        float dv = d > 1 ? (float)d : 1.f;
        eamb[n0 * EDGE_DIM + i] = (_Float16)(((float*)s_e)[i] / dv);
    }
}

// ===========================================================================
// WeWl = We @ Wl (32x128) fp32, beWl = be @ Wl (128) fp32
// ===========================================================================
__global__ void wewl_kernel(const float* __restrict__ We, const float* __restrict__ be,
                            const float* __restrict__ Wl,
                            float* __restrict__ WeWl, float* __restrict__ beWl) {
    int idx = blockIdx.x * 256 + threadIdx.x;
    if (idx >= 33 * 128) return;
    int r = idx >> 7;
    int n = idx & 127;
    float s = 0.f;
    if (r < 32) {
        for (int j = 0; j < 128; ++j) s += We[r * 128 + j] * Wl[j * 128 + n];
        WeWl[r * 128 + n] = s;
    } else {
        for (int j = 0; j < 128; ++j) s += be[j] * Wl[j * 128 + n];
        beWl[n] = s;
    }
}

// ===========================================================================
// Wbig = [Wl(128); Wr(128); WeWl(32)] -> fp16 MFMA B-fragment order, K=288.
// ===========================================================================
__global__ void wbig_swizzle_kernel(const float* __restrict__ Wl,
                                    const float* __restrict__ Wr,
                                    const float* __restrict__ WeWl,
                                    _Float16* __restrict__ Wbs) {
    int idx = blockIdx.x * 256 + threadIdx.x;
    if (idx >= 8 * 9 * 64 * 8) return;  // 36864
    int j = idx & 7;
    int lane = (idx >> 3) & 63;
    int rem = idx >> 9;  // 0..71
    int ks = rem % 9;
    int nt = rem / 9;
    int k = ks * 32 + ((lane >> 4) & 3) * 8 + j;
    int n = nt * 16 + (lane & 15);
    float v = (k < 128) ? Wl[k * 128 + n]
            : (k < 256) ? Wr[(k - 128) * 128 + n]
                        : WeWl[(k - 256) * 128 + n];
    Wbs[idx] = (_Float16)v;
}

// ===========================================================================
// meanb[n] = fp16(mean over in-edges of xin[src]). Block-cooperative:
// 32 nodes/block, s_acc[32][128] fp32 (16 KB), 4 waves walk the contiguous
// CSR range, 8 edges per wave-step, lane owns feature pair 2*lane.
// ===========================================================================
__global__ __launch_bounds__(256) void agg_kernel(const _Float16* __restrict__ xin,
                                                  const int* __restrict__ rowptr,
                                                  const int2* __restrict__ pk,
                                                  _Float16* __restrict__ meanb) {
    __shared__ float s_acc[32][HIDDEN];  // 16 KB
    __shared__ int s_rp[33];
    int t = threadIdx.x;
    int n0 = blockIdx.x * 32;
    if (t <= 32) s_rp[t] = rowptr[n0 + t];
    for (int i = t; i < 32 * HIDDEN; i += 256) ((float*)s_acc)[i] = 0.f;
    __syncthreads();

    int E0 = s_rp[0], E1 = s_rp[32];
    int g = t >> 6;
    int lane = t & 63;
    int f2 = lane * 2;

    for (int pos = E0 + g * 8; pos < E1; pos += 32) {
        int c = E1 - pos; c = c > 8 ? 8 : c;
        int sv[8];
        f16x2 xv[8];
#pragma unroll
        for (int u = 0; u < 8; ++u)
            if (u < c) sv[u] = pk[pos + u].x;
#pragma unroll
        for (int u = 0; u < 8; ++u)
            if (u < c) xv[u] = *(const f16x2*)&xin[(sv[u] & SRC_MASK) * HIDDEN + f2];
#pragma unroll
        for (int u = 0; u < 8; ++u)
            if (u < c) {
                int nl = ((unsigned)sv[u] >> 25) & 31;
                atomicAdd(&s_acc[nl][f2], (float)xv[u].x);
                atomicAdd(&s_acc[nl][f2 + 1], (float)xv[u].y);
            }
    }
    __syncthreads();

    for (int i = t; i < 32 * HIDDEN / 2; i += 256) {  // 2048 f16x2
        int nl = i >> 6;
        int fp = (i & 63) * 2;
        int d = s_rp[nl + 1] - s_rp[nl];
        float dv = d > 1 ? (float)d : 1.f;
        f16x2 o;
        o.x = (_Float16)(s_acc[nl][fp] / dv);
        o.y = (_Float16)(s_acc[nl][fp + 1] / dv);
        *(f16x2*)&meanb[(n0 + nl) * HIDDEN + fp] = o;
    }
}

// ===========================================================================
// Node GEMM via f16 MFMA: out = relu([mean|x|eam] @ [Wl;Wr;WeWl] + bias), K=288.
// ===========================================================================
#define APITCH 296  // 288 + 8 f16 pad
__global__ __launch_bounds__(256) void node_gemm_kernel(
        const _Float16* __restrict__ meanb,
        const _Float16* __restrict__ xb,
        const _Float16* __restrict__ eamb,
        const _Float16* __restrict__ Wbs,
        const int* __restrict__ rowptr,
        const float* __restrict__ bl, const float* __restrict__ br,
        const float* __restrict__ beWl,
        _Float16* __restrict__ outb) {
    __shared__ _Float16 s_a[64 * APITCH];  // 37888 B
    __shared__ float s_bias[128];
    __shared__ float s_bw[128];
    __shared__ int s_deg[64];
    int t = threadIdx.x;
    int n0 = blockIdx.x * 64;

    if (t < 128) {
        s_bias[t] = bl[t] + br[t];
        s_bw[t] = beWl[t];
    } else if (t < 192) {
        int m = t - 128;
        int n = n0 + m;
        n = n < N_NODES ? n : N_NODES - 1;
        s_deg[m] = rowptr[n + 1] - rowptr[n];
    }
    for (int i = t; i < 64 * 16; i += 256) {
        int row = i >> 4, seg = i & 15;
        int n = n0 + row;
        n = n < N_NODES ? n : N_NODES - 1;
        *(f16x8*)&s_a[row * APITCH + seg * 8] = *(const f16x8*)&meanb[n * HIDDEN + seg * 8];
        *(f16x8*)&s_a[row * APITCH + 128 + seg * 8] = *(const f16x8*)&xb[n * HIDDEN + seg * 8];
    }
    for (int i = t; i < 64 * 4; i += 256) {
        int row = i >> 2, seg = i & 3;
        int n = n0 + row;
        n = n < N_NODES ? n : N_NODES - 1;
        *(f16x8*)&s_a[row * APITCH + 256 + seg * 8] = *(const f16x8*)&eamb[n * EDGE_DIM + seg * 8];
    }
    __syncthreads();

    int wave = t >> 6;
    int lane = t & 63;
    int col = lane & 15;
    int kgrp = lane >> 4;

    f32x4 acc[8];
#pragma unroll
    for (int nt = 0; nt < 8; ++nt) acc[nt] = (f32x4){0.f, 0.f, 0.f, 0.f};

    const f16x8* __restrict__ Wb = (const f16x8*)Wbs;
#pragma unroll
    for (int ks = 0; ks < 9; ++ks) {
        f16x8 afrag = *(const f16x8*)&s_a[(wave * 16 + col) * APITCH + ks * 32 + kgrp * 8];
#pragma unroll
        for (int nt = 0; nt < 8; ++nt) {
            f16x8 bfrag = Wb[(nt * 9 + ks) * 64 + lane];
            acc[nt] = __builtin_amdgcn_mfma_f32_16x16x32_f16(afrag, bfrag, acc[nt], 0, 0, 0);
        }
    }

#pragma unroll
    for (int nt = 0; nt < 8; ++nt) {
        int feat = nt * 16 + col;
        float b = s_bias[feat];
        float bw = s_bw[feat];
#pragma unroll
        for (int r = 0; r < 4; ++r) {
            int m = wave * 16 + kgrp * 4 + r;
            int n = n0 + m;
            float v = acc[nt][r] + b + (s_deg[m] > 0 ? bw : 0.f);
            v = v > 0.f ? v : 0.f;
            if (n < N_NODES) outb[n * HIDDEN + feat] = (_Float16)v;
        }
    }
}

// ===========================================================================
// Wp1 -> UV-GEMM B fragments: K=128 (h dims), N=256 (U cols | V cols).
// ===========================================================================
__global__ void wp1uv_swizzle_kernel(const float* __restrict__ Wp1,
                                     _Float16* __restrict__ Wuv) {
    int idx = blockIdx.x * 256 + threadIdx.x;  // 32768
    if (idx >= 32768) return;
    int j = idx & 7;
    int lane = (idx >> 3) & 63;
    int ks = (idx >> 9) & 3;
    int nt = (idx >> 11) & 15;
    int k = ks * 32 + ((lane >> 4) & 3) * 8 + j;
    int n = nt * 16 + (lane & 15);
    float v = (n < 128) ? Wp1[k * 128 + n] : Wp1[(128 + k) * 128 + (n - 128)];
    Wuv[idx] = (_Float16)v;
}

// ===========================================================================
// UV GEMM: UV[n][0:128] = h[n]@Wp1_top + bp1 ; UV[n][128:256] = h[n]@Wp1_bot.
// ===========================================================================
#define UPITCH 136  // 128 + 8 f16 pad
__global__ __launch_bounds__(256) void uv_gemm_kernel(
        const _Float16* __restrict__ h,
        const _Float16* __restrict__ Wuv,
        const float* __restrict__ bp1,
        _Float16* __restrict__ UV) {
    __shared__ _Float16 s_a[64 * UPITCH];  // 17408 B
    __shared__ float s_bias[256];
    int t = threadIdx.x;
    int n0 = blockIdx.x * 64;

    s_bias[t] = (t < 128) ? bp1[t] : 0.f;
    for (int i = t; i < 64 * 16; i += 256) {
        int row = i >> 4, seg = i & 15;
        int n = n0 + row;
        n = n < N_NODES ? n : N_NODES - 1;
        *(f16x8*)&s_a[row * UPITCH + seg * 8] = *(const f16x8*)&h[n * HIDDEN + seg * 8];
    }
    __syncthreads();

    int wave = t >> 6;
    int lane = t & 63;
    int col = lane & 15;
    int kgrp = lane >> 4;

    f32x4 acc[16];
#pragma unroll
    for (int nt = 0; nt < 16; ++nt) acc[nt] = (f32x4){0.f, 0.f, 0.f, 0.f};

    const f16x8* __restrict__ Wb = (const f16x8*)Wuv;
#pragma unroll
    for (int ks = 0; ks < 4; ++ks) {
        f16x8 afrag = *(const f16x8*)&s_a[(wave * 16 + col) * UPITCH + ks * 32 + kgrp * 8];
#pragma unroll
        for (int nt = 0; nt < 16; ++nt) {
            f16x8 bfrag = Wb[(nt * 4 + ks) * 64 + lane];
            acc[nt] = __builtin_amdgcn_mfma_f32_16x16x32_f16(afrag, bfrag, acc[nt], 0, 0, 0);
        }
    }

#pragma unroll
    for (int nt = 0; nt < 16; ++nt) {
        int feat = nt * 16 + col;
        float b = s_bias[feat];
#pragma unroll
        for (int r = 0; r < 4; ++r) {
            int m = wave * 16 + kgrp * 4 + r;
            int n = n0 + m;
            if (n < N_NODES) UV[n * 256 + feat] = (_Float16)(acc[nt][r] + b);
        }
    }
}

// ===========================================================================
// Edge predictor: out[eid] = relu(U[src] + V[dst]) @ Wp2 + bp2.
// 16 edges per wave (2 slots x 8-deep), LDS-free, CSR order (V run-sequential).
// N_EDGES = 64 * 9375 exactly.
// ===========================================================================
__global__ __launch_bounds__(256) void edge_pred_kernel(
        const _Float16* __restrict__ UV,
        const int2* __restrict__ pk,
        const int* __restrict__ pdst,
        const float* __restrict__ Wp2,
        const float* __restrict__ bp2,
        float* __restrict__ out) {
    int t = threadIdx.x;
    int wave = t >> 6;
    int lane = t & 63;
    int slot = lane >> 5;
    int k4 = (lane & 31) * 4;

    float4 wa = *(const float4*)&Wp2[k4 * 2];
    float4 wb = *(const float4*)&Wp2[k4 * 2 + 4];
    float b0 = bp2[0], b1 = bp2[1];

    int e0 = blockIdx.x * 64 + wave * 16;

    int2 pv[8];
    int dn[8];
#pragma unroll
    for (int u = 0; u < 8; ++u) {
        int pos = e0 + 2 * u + slot;
        pv[u] = pk[pos];
        dn[u] = pdst[pos];
    }
    f16x4 uu[8], vv[8];
#pragma unroll
    for (int u = 0; u < 8; ++u) {
        uu[u] = *(const f16x4*)&UV[(pv[u].x & SRC_MASK) * 256 + k4];
        vv[u] = *(const f16x4*)&UV[dn[u] * 256 + 128 + k4];
    }

    float p0[8], p1[8];
#pragma unroll
    for (int u = 0; u < 8; ++u) {
        float z0 = (float)uu[u].x + (float)vv[u].x; z0 = z0 > 0.f ? z0 : 0.f;
        float z1 = (float)uu[u].y + (float)vv[u].y; z1 = z1 > 0.f ? z1 : 0.f;
        float z2 = (float)uu[u].z + (float)vv[u].z; z2 = z2 > 0.f ? z2 : 0.f;
        float z3 = (float)uu[u].w + (float)vv[u].w; z3 = z3 > 0.f ? z3 : 0.f;
        p0[u] = z0 * wa.x + z1 * wa.z + z2 * wb.x + z3 * wb.z;
        p1[u] = z0 * wa.y + z1 * wa.w + z2 * wb.y + z3 * wb.w;
    }
#pragma unroll
    for (int m = 1; m < 32; m <<= 1) {
#pragma unroll
        for (int u = 0; u < 8; ++u) {
            p0[u] += __shfl_xor(p0[u], m);
            p1[u] += __shfl_xor(p1[u], m);
        }
    }
    if ((lane & 31) == 0) {
#pragma unroll
        for (int u = 0; u < 8; ++u) {
            float2 o;
            o.x = p0[u] + b0;
            o.y = p1[u] + b1;
            *(float2*)&out[pv[u].y * 2] = o;
        }
    }
}

// ===========================================================================
extern "C" void kernel_launch(void* const* d_in, const int* in_sizes, int n_in,
                              void* d_out, int out_size, void* d_ws, size_t ws_size,
                              hipStream_t stream) {
    const float* x   = (const float*)d_in[0];
    const int*   ei  = (const int*)d_in[1];
    const float* ea  = (const float*)d_in[2];
    const float* We1 = (const float*)d_in[3];
    const float* be1 = (const float*)d_in[4];
    const float* Wl1 = (const float*)d_in[5];
    const float* bl1 = (const float*)d_in[6];
    const float* Wr1 = (const float*)d_in[7];
    const float* br1 = (const float*)d_in[8];
    const float* We2 = (const float*)d_in[9];
    const float* be2 = (const float*)d_in[10];
    const float* Wl2 = (const float*)d_in[11];
    const float* bl2 = (const float*)d_in[12];
    const float* Wr2 = (const float*)d_in[13];
    const float* br2 = (const float*)d_in[14];
    const float* Wp1 = (const float*)d_in[15];
    const float* bp1 = (const float*)d_in[16];
    const float* Wp2 = (const float*)d_in[17];
    const float* bp2 = (const float*)d_in[18];
    float* out = (float*)d_out;

    const int* src = ei;
    const int* dst = ei + N_EDGES;

    char* ws = (char*)d_ws;
    int*   cnt     = (int*)(ws + 0);           // 409600
    int*   scanout = (int*)(ws + 409600);      // 409600
    int*   bsum    = (int*)(ws + 819200);      // 8192
    int*   rowptr  = (int*)(ws + 827392);      // 409600 (N+1 ints)
    int*   cur     = (int*)(ws + 1236992);     // 409600
    int2*  pk      = (int2*)(ws + 1646592);    // 4800512
    float* WeWl1   = (float*)(ws + 6447104);   // 16384
    float* beWl1   = (float*)(ws + 6463488);   // 512
    float* WeWl2   = (float*)(ws + 6464000);   // 16384
    float* beWl2   = (float*)(ws + 6480384);   // 512
    _Float16* eamb = (_Float16*)(ws + 6480896);   // 6.4 MB
    _Float16* xb   = (_Float16*)(ws + 12880896);  // 25.6 MB
    _Float16* meanb= (_Float16*)(ws + 38480896);  // 25.6 MB
    // UV (51.2 MB) aliases xb+meanb (both dead before uv_gemm)
    _Float16* UV   = (_Float16*)(ws + 12880896);
    _Float16* h1b  = (_Float16*)(ws + 64080896);  // 25.6 MB
    _Float16* h2b  = (_Float16*)(ws + 89680896);  // 25.6 MB
    _Float16* Wbs1 = (_Float16*)(ws + 115280896); // 73728
    _Float16* Wbs2 = (_Float16*)(ws + 115354624); // 73728
    _Float16* Wuv  = (_Float16*)(ws + 115428352); // 65536
    int*   pdst    = (int*)(ws + 115493888);      // 2.4 MB

    const int EB = (N_EDGES + 255) / 256;

    // ---- CSR build ----
    hipMemsetAsync(cnt, 0, N_NODES * sizeof(int), stream);
    hist_kernel<<<EB, 256, 0, stream>>>(dst, cnt);
    scan1_kernel<<<NBLK, 256, 0, stream>>>(cnt, scanout, bsum);
    scan2_kernel<<<1, 512, 0, stream>>>(bsum);
    scan3_kernel<<<NBLK, 256, 0, stream>>>(cnt, scanout, bsum, rowptr, cur);
    fill_kernel<<<EB, 256, 0, stream>>>(src, dst, cur, pk, pdst);

    // ---- graph-invariant precompute ----
    eam_kernel<<<N_NODES / 32, 256, 0, stream>>>(rowptr, pk, ea, eamb);
    wewl_kernel<<<17, 256, 0, stream>>>(We1, be1, Wl1, WeWl1, beWl1);
    wewl_kernel<<<17, 256, 0, stream>>>(We2, be2, Wl2, WeWl2, beWl2);
    xb_kernel<<<(N_NODES * HIDDEN / 2 + 255) / 256, 256, 0, stream>>>(x, xb);
    wbig_swizzle_kernel<<<144, 256, 0, stream>>>(Wl1, Wr1, WeWl1, Wbs1);
    wbig_swizzle_kernel<<<144, 256, 0, stream>>>(Wl2, Wr2, WeWl2, Wbs2);
    wp1uv_swizzle_kernel<<<128, 256, 0, stream>>>(Wp1, Wuv);

    // ---- layer 1 ----
    agg_kernel<<<N_NODES / 32, 256, 0, stream>>>(xb, rowptr, pk, meanb);
    node_gemm_kernel<<<(N_NODES + 63) / 64, 256, 0, stream>>>(
        meanb, xb, eamb, Wbs1, rowptr, bl1, br1, beWl1, h1b);

    // ---- layer 2 ----
    agg_kernel<<<N_NODES / 32, 256, 0, stream>>>(h1b, rowptr, pk, meanb);
    node_gemm_kernel<<<(N_NODES + 63) / 64, 256, 0, stream>>>(
        meanb, h1b, eamb, Wbs2, rowptr, bl2, br2, beWl2, h2b);

    // ---- edge predictor: UV decomposition + streaming edge pass ----
    uv_gemm_kernel<<<(N_NODES + 63) / 64, 256, 0, stream>>>(h2b, Wuv, bp1, UV);
    edge_pred_kernel<<<N_EDGES / 64, 256, 0, stream>>>(UV, pk, pdst, Wp2, bp2, out);
}